// Round 10
// baseline (111.586 us; speedup 1.0000x reference)
//
#include <hip/hip_runtime.h>
#include <hip/hip_bf16.h>

#define N_ENT 100000
#define NB 16
#define DIM 128
#define TILE 128
#define RSTRIDE 132      // 128+4 floats: per-lane b128 reads conflict-free
#define N_TILES ((N_ENT + TILE - 1) / TILE)   // 782
#define NPART (2 * N_TILES)                   // 2 partial slots per (b, block)

// ---------------- kernel 1: head = normalize(ent[e1]) + normalize(rel[r]) ----
__global__ __launch_bounds__(128) void head_kernel(
    const int* __restrict__ e1, const int* __restrict__ rel,
    const float* __restrict__ ent, const float* __restrict__ relemb,
    float* __restrict__ head)
{
    int b = blockIdx.x, d = threadIdx.x;
    float ev = ent[e1[b] * DIM + d];
    float rv = relemb[rel[b] * DIM + d];
    __shared__ float s1[DIM], s2[DIM];
    s1[d] = ev * ev;
    s2[d] = rv * rv;
    __syncthreads();
    for (int s = 64; s > 0; s >>= 1) {
        if (d < s) { s1[d] += s1[d + s]; s2[d] += s2[d + s]; }
        __syncthreads();
    }
    float ne = fmaxf(sqrtf(s1[0]), 1e-12f);
    float nr = fmaxf(sqrtf(s2[0]), 1e-12f);
    head[b * DIM + d] = ev / ne + rv / nr;
}

// ---------------- kernel 2: fused dist + exp; 128-tile, 1024 thr ------------
// 782 blocks, one 128-entity tile each. Block = 16 waves; wave w: entity half
// h2 = w>>3 (64 entities), b-pair g = w&7. LDS 68 KB -> 2 blocks/CU -> 32
// waves/CU = 100% occupancy, same frontier as round 9 but: half the blocks
// (half the stage-latency events), ONE barrier per block (ssq fused into the
// staging pass, computed from registers + 3 shuffles), and per-entity LDS
// wave-instrs cut ~13%. Heads stay wave-uniform -> s_load (scalar pipe).
__global__ __launch_bounds__(1024, 8) void dist_kernel(
    const float* __restrict__ ent, const float* __restrict__ head,
    float* __restrict__ partials, float* __restrict__ out)
{
    __shared__ float ldsRow[TILE * RSTRIDE];   // 67584 B
    __shared__ float ldsInv[TILE];             // 512 B

    const int tid  = threadIdx.x;
    const int lane = tid & 63;
    const int wv   = __builtin_amdgcn_readfirstlane(tid >> 6);  // uniform 0..15
    const int g    = wv & 7;                   // b-pair selector
    const int h2   = wv >> 3;                  // entity half
    const int bbase = g * 2;
    const int n0 = blockIdx.x * TILE;
    const float4* __restrict__ hg = (const float4*)head;  // uniform-indexed

    // stage rows + fused ssq: thread t owns row r = t>>3, f4-cols q+8i.
    // ssq computed from the just-loaded registers (no LDS re-read pass).
    {
        const float4* eg = (const float4*)ent;
        int r = tid >> 3, q = tid & 7;
        int gr = n0 + r;
        if (gr >= N_ENT) gr = N_ENT - 1;       // clamp for partial last tile
        float ssq = 0.f;
        #pragma unroll
        for (int i = 0; i < 4; i++) {
            int c = q + 8 * i;
            float4 v = eg[gr * 32 + c];
            ssq = fmaf(v.x, v.x, fmaf(v.y, v.y, fmaf(v.z, v.z, fmaf(v.w, v.w, ssq))));
            *(float4*)&ldsRow[r * RSTRIDE + c * 4] = v;
        }
        ssq += __shfl_down(ssq, 4);            // 8 threads/row, same wave
        ssq += __shfl_down(ssq, 2);
        ssq += __shfl_down(ssq, 1);
        if (q == 0) ldsInv[r] = 1.0f / fmaxf(sqrtf(ssq), 1e-12f);
    }
    __syncthreads();                           // the ONLY barrier

    const int e = h2 * 64 + lane;              // entity within tile
    const float inv = ldsInv[e];
    const float* rp = &ldsRow[e * RSTRIDE];

    float a0 = 0.f, a1 = 0.f;
    #pragma unroll
    for (int j = 0; j < DIM / 4; j++) {
        float4 v  = *(const float4*)&rp[j * 4];
        float4 q0 = hg[(bbase + 0) * 32 + j];  // uniform -> s_load
        float4 q1 = hg[(bbase + 1) * 32 + j];
        a0 += fabsf(fmaf(-v.x, inv, q0.x)) + fabsf(fmaf(-v.y, inv, q0.y))
            + fabsf(fmaf(-v.z, inv, q0.z)) + fabsf(fmaf(-v.w, inv, q0.w));
        a1 += fabsf(fmaf(-v.x, inv, q1.x)) + fabsf(fmaf(-v.y, inv, q1.y))
            + fabsf(fmaf(-v.z, inv, q1.z)) + fabsf(fmaf(-v.w, inv, q1.w));
    }

    // exp; no max-subtract needed: dist <= 34, sums < 6e19 << fp32 max
    const int n = n0 + e;
    const bool valid = (n < N_ENT);
    float e0 = valid ? __expf(a0) : 0.f;
    float e1 = valid ? __expf(a1) : 0.f;
    if (valid) {
        out[(bbase + 0) * N_ENT + n] = e0;     // lane-contiguous: coalesced
        out[(bbase + 1) * N_ENT + n] = e1;
    }

#define WRED(x) { x += __shfl_down(x, 32); x += __shfl_down(x, 16); \
                  x += __shfl_down(x, 8);  x += __shfl_down(x, 4);  \
                  x += __shfl_down(x, 2);  x += __shfl_down(x, 1); }
    WRED(e0) WRED(e1)
#undef WRED
    if (lane == 0) {   // 2 slots per (b, block): one per entity-half wave
        partials[(bbase + 0) * NPART + 2 * blockIdx.x + h2] = e0;
        partials[(bbase + 1) * NPART + 2 * blockIdx.x + h2] = e1;
    }
}

// ---------------- kernel 3: out *= 1/sum(partials[b][*]) --------------------
// Each block redundantly reduces its row's 1564 partials (6.3 KB, L2-hot).
__global__ __launch_bounds__(256) void scale_kernel(
    float* __restrict__ out, const float* __restrict__ partials)
{
    const int b = blockIdx.y;
    const int tid = threadIdx.x;

    // load my output chunk first (overlaps with the reduction)
    const int i = blockIdx.x * 256 + tid;              // float4 index
    float4 v = make_float4(0.f, 0.f, 0.f, 0.f);
    float4* row = (float4*)&out[b * N_ENT];
    const bool valid = (i < N_ENT / 4);
    if (valid) v = row[i];

    float s = 0.f;
    for (int k = tid; k < NPART; k += 256) s += partials[b * NPART + k];
    s += __shfl_down(s, 32); s += __shfl_down(s, 16);
    s += __shfl_down(s, 8);  s += __shfl_down(s, 4);
    s += __shfl_down(s, 2);  s += __shfl_down(s, 1);
    __shared__ float red[4];
    if ((tid & 63) == 0) red[tid >> 6] = s;
    __syncthreads();
    const float invS = 1.0f / (red[0] + red[1] + red[2] + red[3]);

    if (valid) {
        v.x *= invS; v.y *= invS; v.z *= invS; v.w *= invS;
        row[i] = v;
    }
}

extern "C" void kernel_launch(void* const* d_in, const int* in_sizes, int n_in,
                              void* d_out, int out_size, void* d_ws, size_t ws_size,
                              hipStream_t stream) {
    const int*   e1     = (const int*)d_in[0];
    const int*   rel    = (const int*)d_in[1];
    const float* ent    = (const float*)d_in[4];
    const float* relemb = (const float*)d_in[5];
    float* out = (float*)d_out;

    float* head     = (float*)d_ws;                    // 16*128 f32 = 8192 B
    float* partials = (float*)((char*)d_ws + 8192);    // 16*1564 f32 = 100096 B
    // every partials slot is written before it is read -> no zeroing needed

    head_kernel<<<16, 128, 0, stream>>>(e1, rel, ent, relemb, head);
    dist_kernel<<<N_TILES, 1024, 0, stream>>>(ent, head, partials, out);
    scale_kernel<<<dim3((N_ENT / 4 + 255) / 256, NB), 256, 0, stream>>>(out, partials);
}